// Round 2
// baseline (239.787 us; speedup 1.0000x reference)
//
#include <hip/hip_runtime.h>

// Problem constants (from reference)
#define CC 9605
#define BB 2048
#define LL 8
#define CAND_MAX 384
#define NEGF (-1e30f)

// d_ws layout (unsigned words):
//   wsu[0] = wl entry count (atomic)
//   wsu[1] = (unused; was sniff flags)
//   wsu[4 .. 4+2048) = whitelist entries (col<<8 | mask)
//   byte offset 16384: float partials[BB]
#define WS_PARTIALS_OFF 16384

__device__ __forceinline__ unsigned enc_f(float f) {
  unsigned u = __float_as_uint(f);
  return (u & 0x80000000u) ? ~u : (u | 0x80000000u);
}
__device__ __forceinline__ float dec_u(unsigned e) {
  unsigned u = (e & 0x80000000u) ? (e & 0x7fffffffu) : ~e;
  return __uint_as_float(u);
}
__device__ __forceinline__ float sigm(float z) {
  return 1.0f / (1.0f + __expf(-z));
}

// ---- merged sniff+compact: each block sniffs the whole wl buffer itself
// (307 KB, L2/L3-resident, deterministic -> identical dtype decision per
// block), then compacts its 256-column slice. Drops one kernel launch. ----
//   u8  : byte==1 at offsets %4 != 0        -> flag 1 (and 2)
//   i32 : byte==1 only at offsets %4 == 0   -> flag 2
//   f32 : 0x3f at %4==3, never byte==1      -> flag 8
//   bf16: 0x3f at odd offsets incl %4==1    -> flag 4 (and 8)
__global__ __launch_bounds__(256) void wl_prep(
    const unsigned char* __restrict__ wl, unsigned* __restrict__ wsu) {
  __shared__ unsigned sh_f[4];
  const int tid = threadIdx.x;
  const int lane = tid & 63;
  const int wid = tid >> 6;
  const unsigned* wlw = (const unsigned*)wl;
  const int nwords = (LL * CC) / 4;  // 76840 % 4 == 0
  unsigned f = 0u;
  for (int j = tid; j < nwords; j += 256) {
    unsigned w = wlw[j];
#pragma unroll
    for (int k = 0; k < 4; ++k) {
      unsigned bv = (w >> (8 * k)) & 255u;
      if (bv == 1u)    { f |= 2u; if (k != 0) f |= 1u; }
      if (bv == 0x3fu) { f |= 8u; if (k == 1) f |= 4u; }
    }
  }
#pragma unroll
  for (int off = 32; off >= 1; off >>= 1) f |= __shfl_xor(f, off, 64);
  if (lane == 0) sh_f[wid] = f;
  __syncthreads();
  const unsigned g = sh_f[0] | sh_f[1] | sh_f[2] | sh_f[3];
  const int dt = (g & 1u) ? 0 : (g & 4u) ? 3 : (g & 2u) ? 1 : (g & 8u) ? 2 : 0;
  const int* wl32 = (const int*)wl;
  const float* wlf = (const float*)wl;
  const unsigned short* wlh = (const unsigned short*)wl;
  const int c = blockIdx.x * 256 + tid;
  unsigned m = 0u;
  if (c < CC) {
#pragma unroll
    for (int l = 0; l < LL; ++l) {
      int j = l * CC + c;
      bool on;
      if (dt == 0) on = (wl[j] != 0);
      else if (dt == 1) on = (wl32[j] != 0);
      else if (dt == 2) on = (wlf[j] != 0.0f);
      else on = (wlh[j] != 0);
      if (on) m |= (1u << l);
    }
  }
  unsigned long long bal = __ballot(m != 0u);
  if (bal) {
    unsigned wcnt = (unsigned)__popcll(bal);
    unsigned basep = 0u;
    if (lane == 0) basep = atomicAdd(&wsu[0], wcnt);
    basep = __shfl(basep, 0, 64);
    if (m) {
      unsigned pos = basep + (unsigned)__popcll(bal & ((1ull << lane) - 1ull));
      if (pos < 2048u) wsu[4 + pos] = ((unsigned)c << 8) | m;
    }
  }
}

// 512 threads/block: row is register-resident at ~21 words/thread (uint4
// u[5] + tail) so the live set fits the 64-VGPR cap of launch_bounds(512,8)
// WITHOUT spilling (round-1's 256-thread version needed 41 words/thread and
// the compiler spilled the whole array to scratch: VGPR_Count snapped to 40,
// FETCH rose 5MB, occupancy stuck at 3.5 blocks/CU). Target: 4 blocks x 8
// waves = 32 waves/CU.
__global__ __launch_bounds__(512, 8) void loss_kernel(
    const float* __restrict__ x, const float* __restrict__ y,
    const unsigned* __restrict__ wsu, float* __restrict__ partials) {
  __shared__ unsigned sh_cand[CAND_MAX];
  __shared__ unsigned sh_redM[8];
  __shared__ unsigned sh_redC[8];
  __shared__ unsigned sh_cnt;
  __shared__ unsigned sh_e11;
  __shared__ float sh_wl[8][10];

  const int tid = threadIdx.x;
  const int lane = tid & 63;
  const int wid = tid >> 6;
  const int b = blockIdx.x;
  const long long base = (long long)b * CC;

  // ---- 1a. issue ALL row loads first (max memory-level parallelism) ----
  const int soff = (4 - (b & 3)) & 3;          // (b*9605 + soff) % 4 == 0
  const int ngroups = (CC - soff) >> 2;        // 2400 or 2401
  const int tailn = CC - soff - (ngroups << 2);
  const int m_extra = soff + tailn;            // <= 6 scalar leftovers
  const float4* vp = (const float4*)(x + base + soff);  // 16B aligned
  float4 t[5];
#pragma unroll
  for (int i = 0; i < 4; ++i) t[i] = vp[tid + (i << 9)];  // g <= 2047 < 2400
  const int g4 = tid + (4 << 9);
  const bool v4 = (g4 < ngroups);              // tid < 352 or 353
  if (v4) t[4] = vp[g4];
  float tailv = 0.0f;
  const bool has_tail = (tid < m_extra);
  if (has_tail) {
    int tailcol = (tid < soff) ? tid : (soff + (ngroups << 2) + (tid - soff));
    tailv = x[base + tailcol];
  }

  // ---- 1b. issue whitelist gather loads early (latency hides under the
  //          register-only selection phase below) ----
  const unsigned nu = min(wsu[0], 2048u);
  const unsigned* ents = wsu + 4;
  unsigned ent0 = 0u;
  float gx0 = NEGF, gy0 = 0.0f;
  const bool h0 = (unsigned)tid < nu;
  if (h0) ent0 = ents[tid];
  if (h0) { gx0 = x[base + (ent0 >> 8)]; gy0 = y[base + (ent0 >> 8)]; }

  // ---- 1c. encode IN REGISTERS, track max (no LDS staging, no spill) ----
  uint4 u[5];
  unsigned mx = 0u;
#pragma unroll
  for (int i = 0; i < 4; ++i) {
    u[i].x = enc_f(t[i].x); u[i].y = enc_f(t[i].y);
    u[i].z = enc_f(t[i].z); u[i].w = enc_f(t[i].w);
    mx = max(mx, max(max(u[i].x, u[i].y), max(u[i].z, u[i].w)));
  }
  if (v4) {
    u[4].x = enc_f(t[4].x); u[4].y = enc_f(t[4].y);
    u[4].z = enc_f(t[4].z); u[4].w = enc_f(t[4].w);
    mx = max(mx, max(max(u[4].x, u[4].y), max(u[4].z, u[4].w)));
  } else {
    u[4].x = 0u; u[4].y = 0u; u[4].z = 0u; u[4].w = 0u;  // enc0 < any real
  }
  unsigned et = 0u;
  if (has_tail) { et = enc_f(tailv); mx = max(mx, et); }
  if (tid == 0) sh_cnt = 0u;

  // ---- 2. block max ----
#pragma unroll
  for (int off = 32; off >= 1; off >>= 1) mx = max(mx, __shfl_xor(mx, off, 64));
  if (lane == 0) sh_redM[wid] = mx;
  __syncthreads();
  unsigned Emax = sh_redM[0];
#pragma unroll
  for (int w = 1; w < 8; ++w) Emax = max(Emax, sh_redM[w]);

  // block count of row >= T, purely from registers (uniform result)
  auto blk_count = [&](unsigned T) -> unsigned {
    unsigned cnt = 0u;
#pragma unroll
    for (int i = 0; i < 5; ++i) {
      cnt += (u[i].x >= T) + (u[i].y >= T) + (u[i].z >= T) + (u[i].w >= T);
    }
    cnt += (et >= T);  // et==0 on non-tail threads, T >= 1
#pragma unroll
    for (int off = 32; off >= 1; off >>= 1) cnt += __shfl_xor(cnt, off, 64);
    __syncthreads();                            // guard sh_redC reuse
    if (lane == 0) sh_redC[wid] = cnt;
    __syncthreads();
    unsigned s = sh_redC[0];
#pragma unroll
    for (int w = 1; w < 8; ++w) s += sh_redC[w];
    return s;
  };

  // ---- 3. find window [lo,...] holding rank 11 (typ. 1 probe) ----
  unsigned E11 = 0u;
  bool done = false;
  unsigned lo = (Emax > (1u << 23)) ? (Emax - (1u << 23)) : 1u;
  unsigned hi = Emax + 1u;
  unsigned c = blk_count(lo);
  while (c < 11u && lo > 1u) {
    hi = lo;
    lo = (lo > (1u << 23)) ? (lo - (1u << 23)) : 1u;
    c = blk_count(lo);
  }
  while (c > CAND_MAX) {  // rare: bisect (tie-collapse => exact answer)
    if (hi - lo <= 1u) { E11 = lo; done = true; break; }
    unsigned mid = lo + ((hi - lo) >> 1);
    unsigned cm = blk_count(mid);
    if (cm >= 11u) { lo = mid; c = cm; } else { hi = mid; }
  }

  // ---- 4. scan-compact candidates (>= lo) from registers into sh_cand ----
  if (!done) {
    unsigned nloc = 0u;
#pragma unroll
    for (int i = 0; i < 5; ++i) {
      nloc += (u[i].x >= lo) + (u[i].y >= lo) + (u[i].z >= lo) + (u[i].w >= lo);
    }
    nloc += (et >= lo);
    // wave inclusive prefix scan of nloc
    unsigned scan = nloc;
#pragma unroll
    for (int off = 1; off < 64; off <<= 1) {
      unsigned nn = __shfl_up(scan, off, 64);
      if (lane >= off) scan += nn;
    }
    unsigned wtot = __shfl(scan, 63, 64);
    unsigned basep = 0u;
    if (lane == 0) basep = atomicAdd(&sh_cnt, wtot);
    basep = __shfl(basep, 0, 64);
    unsigned pos = basep + scan - nloc;          // exclusive offset
#pragma unroll
    for (int i = 0; i < 5; ++i) {
      if (u[i].x >= lo) sh_cand[pos++] = u[i].x;
      if (u[i].y >= lo) sh_cand[pos++] = u[i].y;
      if (u[i].z >= lo) sh_cand[pos++] = u[i].z;
      if (u[i].w >= lo) sh_cand[pos++] = u[i].w;
    }
    if (et >= lo) sh_cand[pos++] = et;
    __syncthreads();

    // ---- 5. single-wave register top-11 (no barriers, no LDS latency) ----
    if (wid == 0) {
      unsigned v0[6];                           // 6*64 = 384 = CAND_MAX
#pragma unroll
      for (int j = 0; j < 6; ++j) {
        unsigned idx = (unsigned)lane + 64u * j;
        v0[j] = (idx < c) ? sh_cand[idx] : 0u;
      }
      unsigned ans = 0u;
      for (int r = 0; r < 11; ++r) {
        unsigned lmx = v0[0];
#pragma unroll
        for (int j = 1; j < 6; ++j) lmx = max(lmx, v0[j]);
        unsigned wm = lmx;
#pragma unroll
        for (int off = 32; off >= 1; off >>= 1)
          wm = max(wm, __shfl_xor(wm, off, 64));
        ans = wm;
        if (r < 10) {
          unsigned long long bal = __ballot(lmx == wm);
          int first = (int)__ffsll((long long)bal) - 1;
          if (lane == first) {  // remove ONE instance of wm
            bool rm = false;
#pragma unroll
            for (int j = 0; j < 6; ++j) {
              if (!rm && v0[j] == wm) { v0[j] = 0u; rm = true; }
            }
          }
        }
      }
      if (lane == 0) sh_e11 = ans;
    }
    __syncthreads();
    E11 = sh_e11;
  }

  // ---- 6. whitelist gather accumulate (loads issued in 1b, long arrived) ----
  float lm[8];
#pragma unroll
  for (int l = 0; l < 8; ++l) lm[l] = NEGF;
  unsigned pmask = 0u;  // bits0-7: label present; bits8-15: label has positive
  if (h0) {
    unsigned mk = ent0 & 255u;
    pmask |= mk;
    if (gy0 > 0.0f) pmask |= (mk << 8);
#pragma unroll
    for (int l = 0; l < 8; ++l)
      if ((mk >> l) & 1u) lm[l] = fmaxf(lm[l], gx0);
  }
  // safety net (nu <= ~400 in this problem; loop normally never runs)
  for (unsigned e = (unsigned)tid + 512u; e < nu; e += 512u) {
    unsigned ent = ents[e];
    unsigned mk = ent & 255u;
    float xv = x[base + (ent >> 8)];
    float yv = y[base + (ent >> 8)];
    pmask |= mk;
    if (yv > 0.0f) pmask |= (mk << 8);
#pragma unroll
    for (int l = 0; l < 8; ++l)
      if ((mk >> l) & 1u) lm[l] = fmaxf(lm[l], xv);
  }
#pragma unroll
  for (int off = 32; off >= 1; off >>= 1) {
    pmask |= __shfl_xor(pmask, off, 64);
#pragma unroll
    for (int l = 0; l < 8; ++l) lm[l] = fmaxf(lm[l], __shfl_xor(lm[l], off, 64));
  }
  if (lane == 0) {
#pragma unroll
    for (int l = 0; l < 8; ++l) sh_wl[wid][l] = lm[l];
    sh_wl[wid][8] = __uint_as_float(pmask);
  }
  __syncthreads();

  // ---- 7. epilogue on thread 0: per-row partial (no fences, no atomics) ----
  if (tid == 0) {
    float LM[8];
    unsigned PM = 0u;
#pragma unroll
    for (int l = 0; l < 8; ++l) LM[l] = NEGF;
    for (int w = 0; w < 8; ++w) {
#pragma unroll
      for (int l = 0; l < 8; ++l) LM[l] = fmaxf(LM[l], sh_wl[w][l]);
      PM |= __float_as_uint(sh_wl[w][8]);
    }
    unsigned PR = PM & 255u, PO = (PM >> 8) & 255u;
    float thres = fmaxf(sigm(dec_u(E11)), 0.5f);
    float cmax = NEGF, imax = NEGF, umax = NEGF;
#pragma unroll
    for (int l = 0; l < 8; ++l) {
      if ((PR >> l) & 1u) {
        float ml = sigm(LM[l]);
        umax = fmaxf(umax, ml);
        if ((PO >> l) & 1u) cmax = fmaxf(cmax, ml);
        else imax = fmaxf(imax, ml);
      }
    }
    bool anyc = (PO != 0u);
    bool anyi = (PO != 255u);  // L == 8 labels always exist
    float x1 = anyc ? cmax : thres;
    float x2 = anyc ? (anyi ? fmaxf(imax, thres) : thres)
                    : ((nu > 0u) ? umax : NEGF);
    float coef = anyc ? 1.0f : 0.5f;
    float dd = x2 - x1 + 0.1f;
    float rank = ((dd > 0.0f) ? 2.0f : 1.0f) * sigm(10.0f * dd);
    partials[b] = coef * rank;
  }
}

__global__ void final_reduce(const float* __restrict__ partials,
                             float* __restrict__ out) {
  __shared__ float sh[4];
  const int tid = threadIdx.x;
  const int lane = tid & 63;
  const int wid = tid >> 6;
  float s = 0.0f;
  for (int i = tid; i < BB; i += 256) s += partials[i];
#pragma unroll
  for (int off = 32; off >= 1; off >>= 1) s += __shfl_xor(s, off, 64);
  if (lane == 0) sh[wid] = s;
  __syncthreads();
  if (tid == 0) out[0] = (sh[0] + sh[1] + sh[2] + sh[3]) * (1.0f / (float)BB);
}

extern "C" void kernel_launch(void* const* d_in, const int* in_sizes, int n_in,
                              void* d_out, int out_size, void* d_ws,
                              size_t ws_size, hipStream_t stream) {
  const float* x = (const float*)d_in[0];
  const float* y = (const float*)d_in[1];
  // d_in[2] (y_neg) is faithfully ignored — it never affects the loss.
  const unsigned char* wl = (const unsigned char*)d_in[3];
  float* out = (float*)d_out;
  unsigned* wsu = (unsigned*)d_ws;
  float* partials = (float*)((char*)d_ws + WS_PARTIALS_OFF);

  hipMemsetAsync(d_ws, 0, 16, stream);  // zero wsu[0..3]
  wl_prep<<<(CC + 255) / 256, 256, 0, stream>>>(wl, wsu);
  loss_kernel<<<BB, 512, 0, stream>>>(x, y, wsu, partials);
  final_reduce<<<1, 256, 0, stream>>>(partials, out);
}

// Round 3
// 239.500 us; speedup vs baseline: 1.0012x; 1.0012x over previous
//
#include <hip/hip_runtime.h>

// Problem constants (from reference)
#define CC 9605
#define BB 2048
#define LL 8
#define CAND_MAX 384
#define NEGF (-1e30f)

// d_ws layout (unsigned words):
//   wsu[0] = wl entry count (atomic)
//   wsu[4 .. 4+2048) = whitelist entries (col<<8 | mask)
//   byte offset 16384: float partials[BB]
#define WS_PARTIALS_OFF 16384

__device__ __forceinline__ unsigned enc_f(float f) {
  unsigned u = __float_as_uint(f);
  return (u & 0x80000000u) ? ~u : (u | 0x80000000u);
}
__device__ __forceinline__ float dec_u(unsigned e) {
  unsigned u = (e & 0x80000000u) ? (e & 0x7fffffffu) : ~e;
  return __uint_as_float(u);
}
__device__ __forceinline__ float sigm(float z) {
  return 1.0f / (1.0f + __expf(-z));
}

// ---- merged sniff+compact: each block sniffs the whole wl buffer itself
// (307 KB, L2/L3-resident, deterministic -> identical dtype decision per
// block), then compacts its 256-column slice. ----
//   u8  : byte==1 at offsets %4 != 0        -> flag 1 (and 2)
//   i32 : byte==1 only at offsets %4 == 0   -> flag 2
//   f32 : 0x3f at %4==3, never byte==1      -> flag 8
//   bf16: 0x3f at odd offsets incl %4==1    -> flag 4 (and 8)
__global__ __launch_bounds__(256) void wl_prep(
    const unsigned char* __restrict__ wl, unsigned* __restrict__ wsu) {
  __shared__ unsigned sh_f[4];
  const int tid = threadIdx.x;
  const int lane = tid & 63;
  const int wid = tid >> 6;
  const unsigned* wlw = (const unsigned*)wl;
  const int nwords = (LL * CC) / 4;  // 76840 % 4 == 0
  unsigned f = 0u;
  for (int j = tid; j < nwords; j += 256) {
    unsigned w = wlw[j];
#pragma unroll
    for (int k = 0; k < 4; ++k) {
      unsigned bv = (w >> (8 * k)) & 255u;
      if (bv == 1u)    { f |= 2u; if (k != 0) f |= 1u; }
      if (bv == 0x3fu) { f |= 8u; if (k == 1) f |= 4u; }
    }
  }
#pragma unroll
  for (int off = 32; off >= 1; off >>= 1) f |= __shfl_xor(f, off, 64);
  if (lane == 0) sh_f[wid] = f;
  __syncthreads();
  const unsigned g = sh_f[0] | sh_f[1] | sh_f[2] | sh_f[3];
  const int dt = (g & 1u) ? 0 : (g & 4u) ? 3 : (g & 2u) ? 1 : (g & 8u) ? 2 : 0;
  const int* wl32 = (const int*)wl;
  const float* wlf = (const float*)wl;
  const unsigned short* wlh = (const unsigned short*)wl;
  const int c = blockIdx.x * 256 + tid;
  unsigned m = 0u;
  if (c < CC) {
#pragma unroll
    for (int l = 0; l < LL; ++l) {
      int j = l * CC + c;
      bool on;
      if (dt == 0) on = (wl[j] != 0);
      else if (dt == 1) on = (wl32[j] != 0);
      else if (dt == 2) on = (wlf[j] != 0.0f);
      else on = (wlh[j] != 0);
      if (on) m |= (1u << l);
    }
  }
  unsigned long long bal = __ballot(m != 0u);
  if (bal) {
    unsigned wcnt = (unsigned)__popcll(bal);
    unsigned basep = 0u;
    if (lane == 0) basep = atomicAdd(&wsu[0], wcnt);
    basep = __shfl(basep, 0, 64);
    if (m) {
      unsigned pos = basep + (unsigned)__popcll(bal & ((1ull << lane) - 1ull));
      if (pos < 2048u) wsu[4 + pos] = ((unsigned)c << 8) | m;
    }
  }
}

// Row register-residency, take 3.
// Rounds 1-2 both scratch-allocated the row despite intent (VGPR_Count 40/32,
// far below any live-set estimate): the row ARRAY was captured by reference
// into the blk_count lambda called inside data-dependent while loops ->
// SROA failure -> stack slot. This version has NO arrays and NO lambdas on
// the row path: five named uint4 scalars, statement macros expanded at each
// probe site, 21 static EMITs for compaction. Nothing address-taken.

// encode one float4 into one uint4, folding into running max `mx`
#define ENCMAX(U, T)                                            \
  do {                                                          \
    U.x = enc_f(T.x); U.y = enc_f(T.y);                         \
    U.z = enc_f(T.z); U.w = enc_f(T.w);                         \
    mx = max(mx, max(max(U.x, U.y), max(U.z, U.w)));            \
  } while (0)

#define CNT4(U, T)                                              \
  (((U.x >= (T)) ? 1u : 0u) + ((U.y >= (T)) ? 1u : 0u) +        \
   ((U.z >= (T)) ? 1u : 0u) + ((U.w >= (T)) ? 1u : 0u))

// uniform block-wide count of encoded row values >= T (result in RES)
#define BLK_COUNT(T, RES)                                       \
  do {                                                          \
    unsigned _c = CNT4(u0, (T)) + CNT4(u1, (T)) + CNT4(u2, (T)) \
                + CNT4(u3, (T)) + CNT4(u4, (T))                 \
                + ((et >= (T)) ? 1u : 0u);                      \
    _c += __shfl_xor(_c, 32, 64);                               \
    _c += __shfl_xor(_c, 16, 64);                               \
    _c += __shfl_xor(_c, 8, 64);                                \
    _c += __shfl_xor(_c, 4, 64);                                \
    _c += __shfl_xor(_c, 2, 64);                                \
    _c += __shfl_xor(_c, 1, 64);                                \
    __syncthreads(); /* guard sh_redC reuse */                  \
    if (lane == 0) sh_redC[wid] = _c;                           \
    __syncthreads();                                            \
    RES = sh_redC[0] + sh_redC[1] + sh_redC[2] + sh_redC[3] +   \
          sh_redC[4] + sh_redC[5] + sh_redC[6] + sh_redC[7];    \
  } while (0)

#define EMIT(V)                                                 \
  do {                                                          \
    if ((V) >= lo) sh_cand[pos++] = (V);                        \
  } while (0)

__global__ __launch_bounds__(512) void loss_kernel(
    const float* __restrict__ x, const float* __restrict__ y,
    const unsigned* __restrict__ wsu, float* __restrict__ partials) {
  __shared__ unsigned sh_cand[CAND_MAX];
  __shared__ unsigned sh_redM[8];
  __shared__ unsigned sh_redC[8];
  __shared__ unsigned sh_cnt;
  __shared__ unsigned sh_e11;
  __shared__ float sh_wl[8][10];

  const int tid = threadIdx.x;
  const int lane = tid & 63;
  const int wid = tid >> 6;
  const int b = blockIdx.x;
  const long long base = (long long)b * CC;

  // ---- 1a. issue ALL row loads first (max memory-level parallelism) ----
  const int soff = (4 - (b & 3)) & 3;          // (b*9605 + soff) % 4 == 0
  const int ngroups = (CC - soff) >> 2;        // 2400 or 2401
  const int tailn = CC - soff - (ngroups << 2);
  const int m_extra = soff + tailn;            // <= 6 scalar leftovers
  const float4* vp = (const float4*)(x + base + soff);  // 16B aligned
  float4 t0 = vp[tid];
  float4 t1 = vp[tid + 512];
  float4 t2 = vp[tid + 1024];
  float4 t3 = vp[tid + 1536];                  // 2047 < 2400 always valid
  const int g4 = tid + 2048;
  const bool v4 = (g4 < ngroups);              // tid < 352/353
  float4 t4 = make_float4(0.0f, 0.0f, 0.0f, 0.0f);
  if (v4) t4 = vp[g4];
  float tailv = 0.0f;
  const bool has_tail = (tid < m_extra);
  if (has_tail) {
    int tailcol = (tid < soff) ? tid : (soff + (ngroups << 2) + (tid - soff));
    tailv = x[base + tailcol];
  }

  // ---- 1b. issue whitelist gather loads early (latency hides under the
  //          register-only selection phase below) ----
  const unsigned nu = min(wsu[0], 2048u);
  const unsigned* ents = wsu + 4;
  unsigned ent0 = 0u;
  float gx0 = NEGF, gy0 = 0.0f;
  const bool h0 = (unsigned)tid < nu;
  if (h0) ent0 = ents[tid];
  if (h0) { gx0 = x[base + (ent0 >> 8)]; gy0 = y[base + (ent0 >> 8)]; }

  // ---- 1c. encode into NAMED registers, track max ----
  unsigned mx = 0u;
  uint4 u0, u1, u2, u3, u4;
  ENCMAX(u0, t0);
  ENCMAX(u1, t1);
  ENCMAX(u2, t2);
  ENCMAX(u3, t3);
  if (v4) {
    ENCMAX(u4, t4);
  } else {
    u4.x = 0u; u4.y = 0u; u4.z = 0u; u4.w = 0u;  // raw 0 < enc of any float
  }
  unsigned et = 0u;
  if (has_tail) { et = enc_f(tailv); mx = max(mx, et); }
  if (tid == 0) sh_cnt = 0u;

  // ---- 2. block max ----
  mx = max(mx, __shfl_xor(mx, 32, 64));
  mx = max(mx, __shfl_xor(mx, 16, 64));
  mx = max(mx, __shfl_xor(mx, 8, 64));
  mx = max(mx, __shfl_xor(mx, 4, 64));
  mx = max(mx, __shfl_xor(mx, 2, 64));
  mx = max(mx, __shfl_xor(mx, 1, 64));
  if (lane == 0) sh_redM[wid] = mx;
  __syncthreads();
  unsigned Emax = sh_redM[0];
#pragma unroll
  for (int w = 1; w < 8; ++w) Emax = max(Emax, sh_redM[w]);

  // ---- 3. find window [lo,...] holding rank 11 (typ. 1 probe) ----
  unsigned E11 = 0u;
  bool done = false;
  unsigned lo = (Emax > (1u << 23)) ? (Emax - (1u << 23)) : 1u;
  unsigned hi = Emax + 1u;
  unsigned c;
  BLK_COUNT(lo, c);
  while (c < 11u && lo > 1u) {   // uniform: c, lo derived from shared data
    hi = lo;
    lo = (lo > (1u << 23)) ? (lo - (1u << 23)) : 1u;
    BLK_COUNT(lo, c);
  }
  while (c > CAND_MAX) {  // rare: bisect (tie-collapse => exact answer)
    if (hi - lo <= 1u) { E11 = lo; done = true; break; }
    unsigned mid = lo + ((hi - lo) >> 1);
    unsigned cm;
    BLK_COUNT(mid, cm);
    if (cm >= 11u) { lo = mid; c = cm; } else { hi = mid; }
  }

  // ---- 4. scan-compact candidates (>= lo) from registers into sh_cand ----
  if (!done) {
    unsigned nloc = CNT4(u0, lo) + CNT4(u1, lo) + CNT4(u2, lo) +
                    CNT4(u3, lo) + CNT4(u4, lo) + ((et >= lo) ? 1u : 0u);
    // wave inclusive prefix scan of nloc
    unsigned scan = nloc;
#pragma unroll
    for (int off = 1; off < 64; off <<= 1) {
      unsigned nn = __shfl_up(scan, off, 64);
      if (lane >= off) scan += nn;
    }
    unsigned wtot = __shfl(scan, 63, 64);
    unsigned basep = 0u;
    if (lane == 0) basep = atomicAdd(&sh_cnt, wtot);
    basep = __shfl(basep, 0, 64);
    unsigned pos = basep + scan - nloc;          // exclusive offset
    EMIT(u0.x); EMIT(u0.y); EMIT(u0.z); EMIT(u0.w);
    EMIT(u1.x); EMIT(u1.y); EMIT(u1.z); EMIT(u1.w);
    EMIT(u2.x); EMIT(u2.y); EMIT(u2.z); EMIT(u2.w);
    EMIT(u3.x); EMIT(u3.y); EMIT(u3.z); EMIT(u3.w);
    EMIT(u4.x); EMIT(u4.y); EMIT(u4.z); EMIT(u4.w);
    EMIT(et);
    __syncthreads();

    // ---- 5. single-wave register top-11 (no barriers, no LDS latency) ----
    if (wid == 0) {
      unsigned v0[6];                           // 6*64 = 384 = CAND_MAX
#pragma unroll
      for (int j = 0; j < 6; ++j) {
        unsigned idx = (unsigned)lane + 64u * j;
        v0[j] = (idx < c) ? sh_cand[idx] : 0u;
      }
      unsigned ans = 0u;
      for (int r = 0; r < 11; ++r) {
        unsigned lmx = v0[0];
#pragma unroll
        for (int j = 1; j < 6; ++j) lmx = max(lmx, v0[j]);
        unsigned wm = lmx;
#pragma unroll
        for (int off = 32; off >= 1; off >>= 1)
          wm = max(wm, __shfl_xor(wm, off, 64));
        ans = wm;
        if (r < 10) {
          unsigned long long bal = __ballot(lmx == wm);
          int first = (int)__ffsll((long long)bal) - 1;
          if (lane == first) {  // remove ONE instance of wm
            bool rm = false;
#pragma unroll
            for (int j = 0; j < 6; ++j) {
              if (!rm && v0[j] == wm) { v0[j] = 0u; rm = true; }
            }
          }
        }
      }
      if (lane == 0) sh_e11 = ans;
    }
    __syncthreads();
    E11 = sh_e11;
  }

  // ---- 6. whitelist gather accumulate (loads issued in 1b, long arrived) ----
  float lm[8];
#pragma unroll
  for (int l = 0; l < 8; ++l) lm[l] = NEGF;
  unsigned pmask = 0u;  // bits0-7: label present; bits8-15: label has positive
  if (h0) {
    unsigned mk = ent0 & 255u;
    pmask |= mk;
    if (gy0 > 0.0f) pmask |= (mk << 8);
#pragma unroll
    for (int l = 0; l < 8; ++l)
      if ((mk >> l) & 1u) lm[l] = fmaxf(lm[l], gx0);
  }
  // safety net (nu <= ~400 in this problem; loop normally never runs)
  for (unsigned e = (unsigned)tid + 512u; e < nu; e += 512u) {
    unsigned ent = ents[e];
    unsigned mk = ent & 255u;
    float xv = x[base + (ent >> 8)];
    float yv = y[base + (ent >> 8)];
    pmask |= mk;
    if (yv > 0.0f) pmask |= (mk << 8);
#pragma unroll
    for (int l = 0; l < 8; ++l)
      if ((mk >> l) & 1u) lm[l] = fmaxf(lm[l], xv);
  }
#pragma unroll
  for (int off = 32; off >= 1; off >>= 1) {
    pmask |= __shfl_xor(pmask, off, 64);
#pragma unroll
    for (int l = 0; l < 8; ++l) lm[l] = fmaxf(lm[l], __shfl_xor(lm[l], off, 64));
  }
  if (lane == 0) {
#pragma unroll
    for (int l = 0; l < 8; ++l) sh_wl[wid][l] = lm[l];
    sh_wl[wid][8] = __uint_as_float(pmask);
  }
  __syncthreads();

  // ---- 7. epilogue on thread 0: per-row partial (no fences, no atomics) ----
  if (tid == 0) {
    float LM[8];
    unsigned PM = 0u;
#pragma unroll
    for (int l = 0; l < 8; ++l) LM[l] = NEGF;
    for (int w = 0; w < 8; ++w) {
#pragma unroll
      for (int l = 0; l < 8; ++l) LM[l] = fmaxf(LM[l], sh_wl[w][l]);
      PM |= __float_as_uint(sh_wl[w][8]);
    }
    unsigned PR = PM & 255u, PO = (PM >> 8) & 255u;
    float thres = fmaxf(sigm(dec_u(E11)), 0.5f);
    float cmax = NEGF, imax = NEGF, umax = NEGF;
#pragma unroll
    for (int l = 0; l < 8; ++l) {
      if ((PR >> l) & 1u) {
        float ml = sigm(LM[l]);
        umax = fmaxf(umax, ml);
        if ((PO >> l) & 1u) cmax = fmaxf(cmax, ml);
        else imax = fmaxf(imax, ml);
      }
    }
    bool anyc = (PO != 0u);
    bool anyi = (PO != 255u);  // L == 8 labels always exist
    float x1 = anyc ? cmax : thres;
    float x2 = anyc ? (anyi ? fmaxf(imax, thres) : thres)
                    : ((nu > 0u) ? umax : NEGF);
    float coef = anyc ? 1.0f : 0.5f;
    float dd = x2 - x1 + 0.1f;
    float rank = ((dd > 0.0f) ? 2.0f : 1.0f) * sigm(10.0f * dd);
    partials[b] = coef * rank;
  }
}

__global__ void final_reduce(const float* __restrict__ partials,
                             float* __restrict__ out) {
  __shared__ float sh[4];
  const int tid = threadIdx.x;
  const int lane = tid & 63;
  const int wid = tid >> 6;
  float s = 0.0f;
  for (int i = tid; i < BB; i += 256) s += partials[i];
#pragma unroll
  for (int off = 32; off >= 1; off >>= 1) s += __shfl_xor(s, off, 64);
  if (lane == 0) sh[wid] = s;
  __syncthreads();
  if (tid == 0) out[0] = (sh[0] + sh[1] + sh[2] + sh[3]) * (1.0f / (float)BB);
}

extern "C" void kernel_launch(void* const* d_in, const int* in_sizes, int n_in,
                              void* d_out, int out_size, void* d_ws,
                              size_t ws_size, hipStream_t stream) {
  const float* x = (const float*)d_in[0];
  const float* y = (const float*)d_in[1];
  // d_in[2] (y_neg) is faithfully ignored — it never affects the loss.
  const unsigned char* wl = (const unsigned char*)d_in[3];
  float* out = (float*)d_out;
  unsigned* wsu = (unsigned*)d_ws;
  float* partials = (float*)((char*)d_ws + WS_PARTIALS_OFF);

  hipMemsetAsync(d_ws, 0, 16, stream);  // zero wsu[0..3]
  wl_prep<<<(CC + 255) / 256, 256, 0, stream>>>(wl, wsu);
  loss_kernel<<<BB, 512, 0, stream>>>(x, y, wsu, partials);
  final_reduce<<<1, 256, 0, stream>>>(partials, out);
}

// Round 4
// 220.595 us; speedup vs baseline: 1.0870x; 1.0857x over previous
//
#include <hip/hip_runtime.h>

// Problem constants (from reference)
#define CC 9605
#define BB 2048
#define LL 8
#define CAND_MAX 384
#define NEGF (-1e30f)

// d_ws layout (unsigned words):
//   wsu[0] = wl entry count (atomic)
//   wsu[1] = dtype sniff flags (atomic OR)
//   wsu[4 .. 4+2048) = whitelist entries (col<<8 | mask)
//   byte offset 16384: float partials[BB]
#define WS_PARTIALS_OFF 16384

__device__ __forceinline__ unsigned enc_f(float f) {
  unsigned u = __float_as_uint(f);
  return (u & 0x80000000u) ? ~u : (u | 0x80000000u);
}
__device__ __forceinline__ float dec_u(unsigned e) {
  unsigned u = (e & 0x80000000u) ? (e & 0x7fffffffu) : ~e;
  return __uint_as_float(u);
}
__device__ __forceinline__ float sigm(float z) {
  return 1.0f / (1.0f + __expf(-z));
}
// popcount of mask bits strictly below this lane (64-lane prefix)
__device__ __forceinline__ unsigned prefix_lt(unsigned long long m) {
  unsigned r = __builtin_amdgcn_mbcnt_lo((unsigned)m, 0u);
  return __builtin_amdgcn_mbcnt_hi((unsigned)(m >> 32), r);
}

// ---- dtype sniff (word loads): byte signatures over the raw wl buffer ----
// (separate wide-grid kernel; merging into wl_compact cost +16us total, R2)
//   u8  : byte==1 at offsets %4 != 0        -> flag 1 (and 2)
//   i32 : byte==1 only at offsets %4 == 0   -> flag 2
//   f32 : 0x3f at %4==3, never byte==1      -> flag 8
//   bf16: 0x3f at odd offsets incl %4==1    -> flag 4 (and 8)
__global__ void wl_sniff(const unsigned* __restrict__ wlw,
                         unsigned* __restrict__ wsu) {
  const int nwords = (LL * CC) / 4;  // 76840 % 4 == 0
  const int stride = gridDim.x * blockDim.x;
  unsigned f = 0u;
  for (int j = blockIdx.x * blockDim.x + threadIdx.x; j < nwords; j += stride) {
    unsigned w = wlw[j];
#pragma unroll
    for (int k = 0; k < 4; ++k) {
      unsigned b = (w >> (8 * k)) & 255u;
      if (b == 1u)    { f |= 2u; if (k != 0) f |= 1u; }
      if (b == 0x3fu) { f |= 8u; if (k == 1) f |= 4u; }
    }
  }
#pragma unroll
  for (int off = 32; off >= 1; off >>= 1) f |= __shfl_xor(f, off, 64);
  if ((threadIdx.x & 63) == 0 && f) atomicOr(&wsu[1], f);
}

__global__ void wl_compact(const unsigned char* __restrict__ wl,
                           unsigned* __restrict__ wsu) {
  const int tid = threadIdx.x;
  const int lane = tid & 63;
  const int c = blockIdx.x * 256 + tid;
  const unsigned g = wsu[1];
  const int dt = (g & 1u) ? 0 : (g & 4u) ? 3 : (g & 2u) ? 1 : (g & 8u) ? 2 : 0;
  const int* wl32 = (const int*)wl;
  const float* wlf = (const float*)wl;
  const unsigned short* wlh = (const unsigned short*)wl;
  unsigned m = 0u;
  if (c < CC) {
#pragma unroll
    for (int l = 0; l < LL; ++l) {
      int j = l * CC + c;
      bool on;
      if (dt == 0) on = (wl[j] != 0);
      else if (dt == 1) on = (wl32[j] != 0);
      else if (dt == 2) on = (wlf[j] != 0.0f);
      else on = (wlh[j] != 0);
      if (on) m |= (1u << l);
    }
  }
  unsigned long long bal = __ballot(m != 0u);
  if (bal) {
    unsigned wcnt = (unsigned)__popcll(bal);
    unsigned basep = 0u;
    if (lane == 0) basep = atomicAdd(&wsu[0], wcnt);
    basep = __shfl(basep, 0, 64);
    if (m) {
      unsigned pos = basep + (unsigned)__popcll(bal & ((1ull << lane) - 1ull));
      if (pos < 2048u) wsu[4 + pos] = ((unsigned)c << 8) | m;
    }
  }
}

// Selection-tail rewrite (round 4). Rounds 0-3 proved the ~62-68us floor is
// insensitive to where the row lives (LDS / scratch / registers) and to
// occupancy (34-60%) -> the serial shuffle/barrier tail dominates. This
// version: (1) wave counts via ballot bit-planes (SALU) instead of 6-deep
// shfl reduces; (2) compaction prefix via mbcnt instead of shfl_up chain;
// (3) the 11-round remove-max loop replaced by an exact value binary search
// (<=23 iters, ballots only, no DS, no barrier); (4) whitelist reduce moved
// before the final barrier so waves 1-7 overlap wave 0's search.

// encode one float4 into one uint4, folding into running max `mx`
#define ENCMAX(U, T)                                            \
  do {                                                          \
    U.x = enc_f(T.x); U.y = enc_f(T.y);                         \
    U.z = enc_f(T.z); U.w = enc_f(T.w);                         \
    mx = max(mx, max(max(U.x, U.y), max(U.z, U.w)));            \
  } while (0)

#define CNT4(U, T)                                              \
  (((U.x >= (T)) ? 1u : 0u) + ((U.y >= (T)) ? 1u : 0u) +        \
   ((U.z >= (T)) ? 1u : 0u) + ((U.w >= (T)) ? 1u : 0u))

// uniform block-wide count of encoded row values >= T (result in RES)
// wave sum via 5 ballot bit-planes (cnt <= 21 fits 5 bits) -- no DS ops.
#define BLK_COUNT(T, RES)                                       \
  do {                                                          \
    unsigned _c = CNT4(u0, (T)) + CNT4(u1, (T)) + CNT4(u2, (T)) \
                + CNT4(u3, (T)) + CNT4(u4, (T))                 \
                + ((et >= (T)) ? 1u : 0u);                      \
    unsigned _w = (unsigned)__popcll(__ballot(_c & 1u));        \
    _w += (unsigned)__popcll(__ballot(_c & 2u)) << 1;           \
    _w += (unsigned)__popcll(__ballot(_c & 4u)) << 2;           \
    _w += (unsigned)__popcll(__ballot(_c & 8u)) << 3;           \
    _w += (unsigned)__popcll(__ballot(_c & 16u)) << 4;          \
    __syncthreads(); /* guard sh_redC reuse */                  \
    if (lane == 0) sh_redC[wid] = _w;                           \
    __syncthreads();                                            \
    RES = sh_redC[0] + sh_redC[1] + sh_redC[2] + sh_redC[3] +   \
          sh_redC[4] + sh_redC[5] + sh_redC[6] + sh_redC[7];    \
  } while (0)

#define EMIT(V)                                                 \
  do {                                                          \
    if ((V) >= lo) sh_cand[pos++] = (V);                        \
  } while (0)

__global__ __launch_bounds__(512) void loss_kernel(
    const float* __restrict__ x, const float* __restrict__ y,
    const unsigned* __restrict__ wsu, float* __restrict__ partials) {
  __shared__ unsigned sh_cand[CAND_MAX];
  __shared__ unsigned sh_redM[8];
  __shared__ unsigned sh_redC[8];
  __shared__ unsigned sh_cnt;
  __shared__ float sh_wl[8][10];

  const int tid = threadIdx.x;
  const int lane = tid & 63;
  const int wid = tid >> 6;
  const int b = blockIdx.x;
  const long long base = (long long)b * CC;

  // ---- 1a. issue ALL row loads first (max memory-level parallelism) ----
  const int soff = (4 - (b & 3)) & 3;          // (b*9605 + soff) % 4 == 0
  const int ngroups = (CC - soff) >> 2;        // 2400 or 2401
  const int tailn = CC - soff - (ngroups << 2);
  const int m_extra = soff + tailn;            // <= 6 scalar leftovers
  const float4* vp = (const float4*)(x + base + soff);  // 16B aligned
  float4 t0 = vp[tid];
  float4 t1 = vp[tid + 512];
  float4 t2 = vp[tid + 1024];
  float4 t3 = vp[tid + 1536];                  // 2047 < 2400 always valid
  const int g4 = tid + 2048;
  const bool v4 = (g4 < ngroups);              // tid < 352/353
  float4 t4 = make_float4(0.0f, 0.0f, 0.0f, 0.0f);
  if (v4) t4 = vp[g4];
  float tailv = 0.0f;
  const bool has_tail = (tid < m_extra);
  if (has_tail) {
    int tailcol = (tid < soff) ? tid : (soff + (ngroups << 2) + (tid - soff));
    tailv = x[base + tailcol];
  }

  // ---- 1b. issue whitelist gather loads early (latency hides under the
  //          register-only selection phase below) ----
  const unsigned nu = min(wsu[0], 2048u);
  const unsigned* ents = wsu + 4;
  unsigned ent0 = 0u;
  float gx0 = NEGF, gy0 = 0.0f;
  const bool h0 = (unsigned)tid < nu;
  if (h0) ent0 = ents[tid];
  if (h0) { gx0 = x[base + (ent0 >> 8)]; gy0 = y[base + (ent0 >> 8)]; }

  // ---- 1c. encode into NAMED registers, track max ----
  unsigned mx = 0u;
  uint4 u0, u1, u2, u3, u4;
  ENCMAX(u0, t0);
  ENCMAX(u1, t1);
  ENCMAX(u2, t2);
  ENCMAX(u3, t3);
  if (v4) {
    ENCMAX(u4, t4);
  } else {
    u4.x = 0u; u4.y = 0u; u4.z = 0u; u4.w = 0u;  // raw 0 < enc of any float
  }
  unsigned et = 0u;
  if (has_tail) { et = enc_f(tailv); mx = max(mx, et); }
  if (tid == 0) sh_cnt = 0u;

  // ---- 2. block max (values need shuffles; counts below use ballots) ----
  mx = max(mx, __shfl_xor(mx, 32, 64));
  mx = max(mx, __shfl_xor(mx, 16, 64));
  mx = max(mx, __shfl_xor(mx, 8, 64));
  mx = max(mx, __shfl_xor(mx, 4, 64));
  mx = max(mx, __shfl_xor(mx, 2, 64));
  mx = max(mx, __shfl_xor(mx, 1, 64));
  if (lane == 0) sh_redM[wid] = mx;
  __syncthreads();
  unsigned Emax = sh_redM[0];
#pragma unroll
  for (int w = 1; w < 8; ++w) Emax = max(Emax, sh_redM[w]);

  // ---- 3. find window [lo,hi) with count(>=lo)>=11 > count(>=hi) ----
  unsigned E11 = 0u;
  bool done = false;
  unsigned lo = (Emax > (1u << 23)) ? (Emax - (1u << 23)) : 1u;
  unsigned hi = Emax + 1u;
  unsigned c;
  BLK_COUNT(lo, c);
  while (c < 11u && lo > 1u) {   // uniform: c, lo derived from shared data
    hi = lo;
    lo = (lo > (1u << 23)) ? (lo - (1u << 23)) : 1u;
    BLK_COUNT(lo, c);
  }
  while (c > CAND_MAX) {  // rare: bisect (tie-collapse => exact answer)
    if (hi - lo <= 1u) { E11 = lo; done = true; break; }
    unsigned mid = lo + ((hi - lo) >> 1);
    unsigned cm;
    BLK_COUNT(mid, cm);
    if (cm >= 11u) { lo = mid; c = cm; } else { hi = mid; }
  }

  // ---- 4. compact candidates (>= lo) into sh_cand; prefix via mbcnt ----
  if (!done) {
    unsigned nloc = CNT4(u0, lo) + CNT4(u1, lo) + CNT4(u2, lo) +
                    CNT4(u3, lo) + CNT4(u4, lo) + ((et >= lo) ? 1u : 0u);
    unsigned long long m0 = __ballot(nloc & 1u);
    unsigned long long m1 = __ballot(nloc & 2u);
    unsigned long long m2 = __ballot(nloc & 4u);
    unsigned long long m3 = __ballot(nloc & 8u);
    unsigned long long m4 = __ballot(nloc & 16u);
    unsigned wtot = (unsigned)__popcll(m0) + ((unsigned)__popcll(m1) << 1) +
                    ((unsigned)__popcll(m2) << 2) +
                    ((unsigned)__popcll(m3) << 3) +
                    ((unsigned)__popcll(m4) << 4);
    unsigned pre = prefix_lt(m0) + (prefix_lt(m1) << 1) +
                   (prefix_lt(m2) << 2) + (prefix_lt(m3) << 3) +
                   (prefix_lt(m4) << 4);
    unsigned basep = 0u;
    if (lane == 0) basep = atomicAdd(&sh_cnt, wtot);
    basep = (unsigned)__builtin_amdgcn_readfirstlane((int)basep);
    unsigned pos = basep + pre;                  // exclusive offset
    EMIT(u0.x); EMIT(u0.y); EMIT(u0.z); EMIT(u0.w);
    EMIT(u1.x); EMIT(u1.y); EMIT(u1.z); EMIT(u1.w);
    EMIT(u2.x); EMIT(u2.y); EMIT(u2.z); EMIT(u2.w);
    EMIT(u3.x); EMIT(u3.y); EMIT(u3.z); EMIT(u3.w);
    EMIT(u4.x); EMIT(u4.y); EMIT(u4.z); EMIT(u4.w);
    EMIT(et);
    __syncthreads();
  }

  // ---- 5. whitelist reduce for ALL waves (independent of E11; overlaps
  //          wave 0's binary search below) ----
  {
    float lm[8];
#pragma unroll
    for (int l = 0; l < 8; ++l) lm[l] = NEGF;
    unsigned pmask = 0u;  // bits0-7: label present; bits8-15: has positive
    if (h0) {
      unsigned mk = ent0 & 255u;
      pmask |= mk;
      if (gy0 > 0.0f) pmask |= (mk << 8);
#pragma unroll
      for (int l = 0; l < 8; ++l)
        if ((mk >> l) & 1u) lm[l] = fmaxf(lm[l], gx0);
    }
    // safety net (nu <= ~400 here; loop normally never runs)
    for (unsigned e = (unsigned)tid + 512u; e < nu; e += 512u) {
      unsigned ent = ents[e];
      unsigned mk = ent & 255u;
      float xv = x[base + (ent >> 8)];
      float yv = y[base + (ent >> 8)];
      pmask |= mk;
      if (yv > 0.0f) pmask |= (mk << 8);
#pragma unroll
      for (int l = 0; l < 8; ++l)
        if ((mk >> l) & 1u) lm[l] = fmaxf(lm[l], xv);
    }
#pragma unroll
    for (int off = 32; off >= 1; off >>= 1) {
      pmask |= __shfl_xor(pmask, off, 64);
#pragma unroll
      for (int l = 0; l < 8; ++l)
        lm[l] = fmaxf(lm[l], __shfl_xor(lm[l], off, 64));
    }
    if (lane == 0) {
#pragma unroll
      for (int l = 0; l < 8; ++l) sh_wl[wid][l] = lm[l];
      sh_wl[wid][8] = __uint_as_float(pmask);
    }
  }

  // ---- 6. wave 0: exact 11th-largest by value binary search over the
  //          compacted candidates. Ballot counts only: no DS, no barriers.
  //          Invariant: count(>=lo) >= 11 > count(>=hi); window <= 2^23
  //          -> <= 23 iterations. E11 stays in registers (thread 0 uses it).
  if (!done && wid == 0) {
    unsigned c0 = ((unsigned)lane < c) ? sh_cand[lane] : 0u;
    unsigned c1 = ((unsigned)lane + 64u < c) ? sh_cand[lane + 64u] : 0u;
    unsigned c2 = ((unsigned)lane + 128u < c) ? sh_cand[lane + 128u] : 0u;
    unsigned c3 = ((unsigned)lane + 192u < c) ? sh_cand[lane + 192u] : 0u;
    unsigned c4 = ((unsigned)lane + 256u < c) ? sh_cand[lane + 256u] : 0u;
    unsigned c5 = ((unsigned)lane + 320u < c) ? sh_cand[lane + 320u] : 0u;
    unsigned blo = lo, bhi = hi;
    while (bhi - blo > 1u) {
      unsigned mid = blo + ((bhi - blo) >> 1);
      unsigned cnt = (unsigned)__popcll(__ballot(c0 >= mid)) +
                     (unsigned)__popcll(__ballot(c1 >= mid)) +
                     (unsigned)__popcll(__ballot(c2 >= mid)) +
                     (unsigned)__popcll(__ballot(c3 >= mid)) +
                     (unsigned)__popcll(__ballot(c4 >= mid)) +
                     (unsigned)__popcll(__ballot(c5 >= mid));
      if (cnt >= 11u) blo = mid; else bhi = mid;
    }
    E11 = blo;  // largest T with count(>=T) >= 11 == the 11th largest value
  }
  __syncthreads();

  // ---- 7. epilogue on thread 0: per-row partial (E11 is in its regs) ----
  if (tid == 0) {
    float LM[8];
    unsigned PM = 0u;
#pragma unroll
    for (int l = 0; l < 8; ++l) LM[l] = NEGF;
    for (int w = 0; w < 8; ++w) {
#pragma unroll
      for (int l = 0; l < 8; ++l) LM[l] = fmaxf(LM[l], sh_wl[w][l]);
      PM |= __float_as_uint(sh_wl[w][8]);
    }
    unsigned PR = PM & 255u, PO = (PM >> 8) & 255u;
    float thres = fmaxf(sigm(dec_u(E11)), 0.5f);
    float cmax = NEGF, imax = NEGF, umax = NEGF;
#pragma unroll
    for (int l = 0; l < 8; ++l) {
      if ((PR >> l) & 1u) {
        float ml = sigm(LM[l]);
        umax = fmaxf(umax, ml);
        if ((PO >> l) & 1u) cmax = fmaxf(cmax, ml);
        else imax = fmaxf(imax, ml);
      }
    }
    bool anyc = (PO != 0u);
    bool anyi = (PO != 255u);  // L == 8 labels always exist
    float x1 = anyc ? cmax : thres;
    float x2 = anyc ? (anyi ? fmaxf(imax, thres) : thres)
                    : ((nu > 0u) ? umax : NEGF);
    float coef = anyc ? 1.0f : 0.5f;
    float dd = x2 - x1 + 0.1f;
    float rank = ((dd > 0.0f) ? 2.0f : 1.0f) * sigm(10.0f * dd);
    partials[b] = coef * rank;
  }
}

__global__ void final_reduce(const float* __restrict__ partials,
                             float* __restrict__ out) {
  __shared__ float sh[4];
  const int tid = threadIdx.x;
  const int lane = tid & 63;
  const int wid = tid >> 6;
  float s = 0.0f;
  for (int i = tid; i < BB; i += 256) s += partials[i];
#pragma unroll
  for (int off = 32; off >= 1; off >>= 1) s += __shfl_xor(s, off, 64);
  if (lane == 0) sh[wid] = s;
  __syncthreads();
  if (tid == 0) out[0] = (sh[0] + sh[1] + sh[2] + sh[3]) * (1.0f / (float)BB);
}

extern "C" void kernel_launch(void* const* d_in, const int* in_sizes, int n_in,
                              void* d_out, int out_size, void* d_ws,
                              size_t ws_size, hipStream_t stream) {
  const float* x = (const float*)d_in[0];
  const float* y = (const float*)d_in[1];
  // d_in[2] (y_neg) is faithfully ignored — it never affects the loss.
  const unsigned char* wl = (const unsigned char*)d_in[3];
  float* out = (float*)d_out;
  unsigned* wsu = (unsigned*)d_ws;
  float* partials = (float*)((char*)d_ws + WS_PARTIALS_OFF);

  hipMemsetAsync(d_ws, 0, 16, stream);  // zero wsu[0..3]
  wl_sniff<<<64, 256, 0, stream>>>((const unsigned*)wl, wsu);
  wl_compact<<<(CC + 255) / 256, 256, 0, stream>>>(wl, wsu);
  loss_kernel<<<BB, 512, 0, stream>>>(x, y, wsu, partials);
  final_reduce<<<1, 256, 0, stream>>>(partials, out);
}